// Round 5
// baseline (14129.245 us; speedup 1.0000x reference)
//
#include <hip/hip_runtime.h>
#include <hip/hip_bf16.h>
#include <math.h>

#define EPSF 1e-7f
#define MAXNRM 0.99999f

static constexpr int Bb = 16, Ss = 128, Hh = 512, Vv = 10000, Ll = 3;
static constexpr int Nn = Bb * Ss; // 2048
static constexpr int NBLK = 16;    // scan blocks (hidden-dim split)

typedef __attribute__((ext_vector_type(8))) short short8v;
typedef __attribute__((ext_vector_type(4))) float f32x4;

__device__ inline float4 ld4(const float* p){ return *(const float4*)p; }
__device__ inline void st4(float* p, float4 v){ *(float4*)p = v; }
__device__ inline float dot4(float4 a, float4 b){ return a.x*b.x + a.y*b.y + a.z*b.z + a.w*b.w; }
__device__ inline float sigm(float x){ return 1.f/(1.f + expf(-x)); }
__device__ inline unsigned short f2bf(float f){
  __hip_bfloat16 h = __float2bfloat16(f);
  return __builtin_bit_cast(unsigned short, h);
}
__device__ inline float bf2f(short s){
  unsigned x = ((unsigned)(unsigned short)s) << 16;
  return __builtin_bit_cast(float, x);
}
__device__ inline float rsum64f(float v){
  v+=__shfl_xor(v,32); v+=__shfl_xor(v,16); v+=__shfl_xor(v,8);
  v+=__shfl_xor(v,4);  v+=__shfl_xor(v,2);  v+=__shfl_xor(v,1); return v;
}

// ---- coherent (bypass local L1/L2) memory ops via sc0 sc1 ----
__device__ inline void stg_sc(float* p, float v){
  asm volatile("global_store_dword %0, %1, off sc0 sc1" :: "v"(p), "v"(v) : "memory");
}
__device__ inline void ldg_sc8(const float* p, f32x4& a, f32x4& b){
  asm volatile(
    "global_load_dwordx4 %0, %2, off sc0 sc1\n\t"
    "global_load_dwordx4 %1, %2, off offset:16 sc0 sc1\n\t"
    "s_waitcnt vmcnt(0)"
    : "=&v"(a), "=&v"(b) : "v"(p) : "memory");
}
__device__ inline void ldg_sc8x2(const float* p0, const float* p1,
                                 f32x4& a, f32x4& b, f32x4& c, f32x4& d){
  asm volatile(
    "global_load_dwordx4 %0, %4, off sc0 sc1\n\t"
    "global_load_dwordx4 %1, %4, off offset:16 sc0 sc1\n\t"
    "global_load_dwordx4 %2, %5, off sc0 sc1\n\t"
    "global_load_dwordx4 %3, %5, off offset:16 sc0 sc1\n\t"
    "s_waitcnt vmcnt(0)"
    : "=&v"(a), "=&v"(b), "=&v"(c), "=&v"(d) : "v"(p0), "v"(p1) : "memory");
}

// ---------------- pack W[l][j][k] -> bf16 MFMA B-fragments per scan-block ----------------
__global__ void k_pack(const float* __restrict__ Wr, const float* __restrict__ Wz,
                       const float* __restrict__ Wh, ushort* __restrict__ Wp){
  int g = blockIdx.x, lm = blockIdx.y;
  int l = lm/3, mat = lm%3;
  const float* W = (mat==0?Wr:mat==1?Wz:Wh) + (size_t)l*Hh*Hh;
  int tid = threadIdx.x;
  int kt = tid>>6, lane = tid&63, q = (lane>>4)&3, nl = lane&15;
  #pragma unroll
  for(int nt=0;nt<2;nt++){
    int j = g*32 + nt*16 + nl;
    int k0 = kt*32 + q*8;
    const float* src = W + (size_t)j*Hh + k0;
    union { ushort u[8]; uint4 v; } tmp;
    #pragma unroll
    for(int i=0;i<8;i++) tmp.u[i] = f2bf(src[i]);
    size_t off = ((((((size_t)l*NBLK + g)*3 + mat)*16 + kt)*2 + nt)*64 + lane)*8;
    *(uint4*)(Wp + off) = tmp.v;
  }
}

// ---------------- per-(t,b) input-only dots ----------------
__global__ void k_predots(const float* __restrict__ XR, const float* __restrict__ XZ,
                          const float* __restrict__ XH,
                          const float* __restrict__ br, const float* __restrict__ bz,
                          const float* __restrict__ bh, float* __restrict__ pubX){
  int n = blockIdx.x; int tid = threadIdx.x; // 128 threads
  float s0=0,s1=0,s2=0,s3=0,s4=0,s5=0;
  for(int i=tid;i<Hh;i+=128){
    float xr=XR[(size_t)n*Hh+i], xz=XZ[(size_t)n*Hh+i], xh=XH[(size_t)n*Hh+i];
    s0+=xr*xr; s1+=xr*br[i]; s2+=xz*xz; s3+=xz*bz[i]; s4+=xh*xh; s5+=xh*bh[i];
  }
  __shared__ float red[2][6];
  s0=rsum64f(s0); s1=rsum64f(s1); s2=rsum64f(s2);
  s3=rsum64f(s3); s4=rsum64f(s4); s5=rsum64f(s5);
  int w = tid>>6;
  if((tid&63)==0){ red[w][0]=s0; red[w][1]=s1; red[w][2]=s2; red[w][3]=s3; red[w][4]=s4; red[w][5]=s5; }
  __syncthreads();
  if(tid==0){
    #pragma unroll
    for(int d=0;d<6;d++) pubX[(size_t)n*6+d] = red[0][d]+red[1][d];
  }
}

// ---------------- per-vocab constants ----------------
__global__ void k_pav(const float* __restrict__ P, const float* __restrict__ A,
                      float* __restrict__ pp, float* __restrict__ aa, float* __restrict__ pa){
  int w = threadIdx.x >> 6, lane = threadIdx.x & 63;
  int v = blockIdx.x*4 + w;
  const float4* Pr = (const float4*)(P + (size_t)v*Hh);
  const float4* Ar = (const float4*)(A + (size_t)v*Hh);
  float sp=0, sa=0, spa=0;
  #pragma unroll
  for(int i=0;i<2;i++){
    int k4 = lane*2 + i;
    float4 pv = Pr[k4], av = Ar[k4];
    sp += dot4(pv,pv); sa += dot4(av,av); spa += dot4(pv,av);
  }
  for(int o=32;o;o>>=1){ sp+=__shfl_down(sp,o); sa+=__shfl_down(sa,o); spa+=__shfl_down(spa,o); }
  if(lane==0){ pp[v]=sp; aa[v]=sqrtf(sa+EPSF); pa[v]=spa; }
}

// ---------------- embedding gather ----------------
__global__ void k_embed(const int* __restrict__ inp, const float* __restrict__ E, float* __restrict__ X){
  int n = blockIdx.x; int t = n >> 4, b = n & 15;
  int tok = inp[b*Ss + t];
  int i = threadIdx.x;
  st4(X + (size_t)n*Hh + i*4, ld4(E + (size_t)tok*Hh + i*4));
}

// ---------------- row logmap0 ----------------
__global__ void k_logmap(const float* __restrict__ X, float* __restrict__ LX){
  int n = blockIdx.x; int t = threadIdx.x;
  __shared__ float sred[2];
  float4 v = ld4(X + (size_t)n*Hh + t*4);
  float ss = dot4(v,v);
  for(int o=32;o;o>>=1) ss += __shfl_down(ss,o);
  if((t&63)==0) sred[t>>6] = ss;
  __syncthreads();
  ss = sred[0]+sred[1];
  float nn = sqrtf(ss + EPSF);
  float sc = atanhf(fminf(nn, MAXNRM)) / nn;
  v.x*=sc; v.y*=sc; v.z*=sc; v.w*=sc;
  st4(LX + (size_t)n*Hh + t*4, v);
}

// ---------------- row expmap0 (in place, 3 buffers) ----------------
__global__ void k_expmap(float* __restrict__ XR, float* __restrict__ XZ, float* __restrict__ XH){
  float* Xp = blockIdx.y==0 ? XR : (blockIdx.y==1 ? XZ : XH);
  int n = blockIdx.x; int t = threadIdx.x;
  __shared__ float sred[2];
  float4 v = ld4(Xp + (size_t)n*Hh + t*4);
  float ss = dot4(v,v);
  for(int o=32;o;o>>=1) ss += __shfl_down(ss,o);
  if((t&63)==0) sred[t>>6] = ss;
  __syncthreads();
  ss = sred[0]+sred[1];
  float nn = sqrtf(ss + EPSF);
  float sc = tanhf(nn) / nn;
  v.x*=sc; v.y*=sc; v.z*=sc; v.w*=sc;
  st4(Xp + (size_t)n*Hh + t*4, v);
}

// ---------------- GEMM: LX[2048,512] @ {Ur|Uz|Uh}^T ----------------
__global__ __launch_bounds__(256) void k_gemm(const float* __restrict__ A4,
    const float* __restrict__ U0, const float* __restrict__ U1, const float* __restrict__ U2,
    float* __restrict__ O0, float* __restrict__ O1, float* __restrict__ O2){
  __shared__ float As[16][65], Bs[16][65];
  int jb = blockIdx.x;
  int nb = blockIdx.y;
  int mat = jb >> 3; int j0 = (jb & 7)*64;
  const float* Bm = mat==0?U0 : (mat==1?U1:U2);
  float* Om       = mat==0?O0 : (mat==1?O1:O2);
  int tid = threadIdx.x;
  int lr = tid >> 2, lq = tid & 3;
  int tx = tid & 15, ty = tid >> 4;
  float acc[4][4] = {};
  for(int kb=0; kb<Hh; kb+=16){
    float4 av = ld4(A4 + (size_t)(nb*64+lr)*Hh + kb + lq*4);
    float4 bv = ld4(Bm + (size_t)(j0+lr)*Hh + kb + lq*4);
    As[lq*4+0][lr]=av.x; As[lq*4+1][lr]=av.y; As[lq*4+2][lr]=av.z; As[lq*4+3][lr]=av.w;
    Bs[lq*4+0][lr]=bv.x; Bs[lq*4+1][lr]=bv.y; Bs[lq*4+2][lr]=bv.z; Bs[lq*4+3][lr]=bv.w;
    __syncthreads();
    #pragma unroll
    for(int kk=0;kk<16;kk++){
      float a0=As[kk][ty*4+0], a1=As[kk][ty*4+1], a2=As[kk][ty*4+2], a3=As[kk][ty*4+3];
      float b0=Bs[kk][tx*4+0], b1=Bs[kk][tx*4+1], b2=Bs[kk][tx*4+2], b3=Bs[kk][tx*4+3];
      acc[0][0]+=a0*b0; acc[0][1]+=a0*b1; acc[0][2]+=a0*b2; acc[0][3]+=a0*b3;
      acc[1][0]+=a1*b0; acc[1][1]+=a1*b1; acc[1][2]+=a1*b2; acc[1][3]+=a1*b3;
      acc[2][0]+=a2*b0; acc[2][1]+=a2*b1; acc[2][2]+=a2*b2; acc[2][3]+=a2*b3;
      acc[3][0]+=a3*b0; acc[3][1]+=a3*b1; acc[3][2]+=a3*b2; acc[3][3]+=a3*b3;
    }
    __syncthreads();
  }
  for(int i=0;i<4;i++)
    for(int j2=0;j2<4;j2++)
      Om[(size_t)(nb*64+ty*4+i)*Hh + j0 + tx*4 + j2] = acc[i][j2];
}

// ---------------- cooperative hidden-split GRU scan, 2 dependent rounds/step ----------------
// 16 blocks x 1024 threads. Block g owns hidden cols [g*32, g*32+32).
// h is fully replicated; only the three matvec outputs are exchanged (slices out, full in).
__global__ __launch_bounds__(1024) void k_scan5(
    const float* __restrict__ XR, const float* __restrict__ XZ, const float* __restrict__ XH,
    const ushort* __restrict__ Wp_l,
    const float* __restrict__ br, const float* __restrict__ bz, const float* __restrict__ bh,
    const float* __restrict__ pubX,
    float* __restrict__ Emr, float* __restrict__ Emz, float* __restrict__ Emh,
    int* __restrict__ cnt, float* __restrict__ Xout){
  const int g = blockIdx.x;
  const int tid = threadIdx.x;
  const int lane = tid & 63, wv = tid >> 6;  // 16 waves
  const int q = (lane>>4)&3, nl = lane&15;

  __shared__ ushort Wlds[3*16*2*64*8];       // 96 KB
  __shared__ ushort afAF[16*64*8];           // 16 KB A-frag (lh / ap)
  __shared__ float biasL0[Hh], biasL1[Hh], biasL2[Hh];
  __shared__ float part[16][16][18];         // wave partial dots
  __shared__ float dotsA[16][8];
  __shared__ float dotsB[16][18];
  __shared__ float coefA[16][8];
  __shared__ float coefB[16][8];
  __shared__ float ShT[16];
  __shared__ float bbT[4];

  {
    const uint4* srcW = (const uint4*)(Wp_l + (size_t)g*49152);
    uint4* dstW = (uint4*)Wlds;
    #pragma unroll
    for(int i=0;i<6;i++) dstW[i*1024+tid] = srcW[i*1024+tid];
  }
  for(int i=tid;i<Hh;i+=1024){ biasL0[i]=br[i]; biasL1[i]=bz[i]; biasL2[i]=bh[i]; }
  { uint4 z4 = {0,0,0,0}; ((uint4*)afAF)[tid] = z4; }
  if(tid<16) ShT[tid] = 0.f;
  __syncthreads();
  // bias grams (block-local, redundant across blocks)
  {
    float p0=0,p1=0,p2=0;
    if(tid<512){ float a=biasL0[tid],b2=biasL1[tid],c2=biasL2[tid]; p0=a*a; p1=b2*b2; p2=c2*c2; }
    p0=rsum64f(p0); p1=rsum64f(p1); p2=rsum64f(p2);
    if(tid<512 && (tid&63)==0){ dotsB[tid>>6][0]=p0; dotsB[tid>>6][1]=p1; dotsB[tid>>6][2]=p2; }
    __syncthreads();
    if(tid==0){
      float a=0,b2=0,c2=0;
      for(int i=0;i<8;i++){ a+=dotsB[i][0]; b2+=dotsB[i][1]; c2+=dotsB[i][2]; }
      bbT[0]=a; bbT[1]=b2; bbT[2]=c2;
    }
    __syncthreads();
  }

  // per-thread replicated state: h for (row=nl, k = wv*32+q*8 .. +8)
  float hreg[8];
  #pragma unroll
  for(int i=0;i<8;i++) hreg[i]=0.f;

  auto gsync = [&](int idx){
    asm volatile("s_waitcnt vmcnt(0) lgkmcnt(0)" ::: "memory");
    __syncthreads();
    if(tid==0){
      __hip_atomic_fetch_add(cnt+idx, 1, __ATOMIC_RELAXED, __HIP_MEMORY_SCOPE_AGENT);
      while(__hip_atomic_load(cnt+idx, __ATOMIC_RELAXED, __HIP_MEMORY_SCOPE_AGENT) < NBLK)
        __builtin_amdgcn_s_sleep(1);
    }
    __syncthreads();
  };

  const int k8 = wv*32 + q*8;

  for(int ts=0; ts<Ss; ts++){
    const size_t rb16 = (size_t)(ts*Bb)*Hh;
    const size_t rxb = rb16 + (size_t)nl*Hh + k8;

    // prefetch cached x rows for this thread's slot (overlaps MFMA + barrier)
    f32x4 xr0 = *(const f32x4*)(XR + rxb), xr1 = *(const f32x4*)(XR + rxb + 4);
    f32x4 xz0 = *(const f32x4*)(XZ + rxb), xz1 = *(const f32x4*)(XZ + rxb + 4);
    f32x4 xh0 = *(const f32x4*)(XH + rxb), xh1 = *(const f32x4*)(XH + rxb + 4);

    // ---- P2: matvec r/z via MFMA (waves 0..3), publish own slices ----
    if(wv < 4){
      int mat = wv>>1, nt = wv&1;
      f32x4 acc = {0.f,0.f,0.f,0.f};
      #pragma unroll
      for(int kt2=0;kt2<16;kt2++){
        short8v av = *(const short8v*)&afAF[((size_t)kt2*64+lane)*8];
        short8v bv = *(const short8v*)&Wlds[((((size_t)mat*16+kt2)*2+nt)*64+lane)*8];
        acc = __builtin_amdgcn_mfma_f32_16x16x32_bf16(av, bv, acc, 0,0,0);
      }
      float* pdst = (mat==0)? Emr : Emz;
      int colg = g*32 + nt*16 + nl;
      #pragma unroll
      for(int rr=0;rr<4;rr++)
        stg_sc(pdst + (q*4+rr)*Hh + colg, acc[rr]);
    }
    gsync(2*ts);  // ---- sync A ----

    // ---- round A load: full mr, mz into regs ----
    f32x4 mr0,mr1,mz0,mz1;
    ldg_sc8x2(Emr + nl*Hh + k8, Emz + nl*Hh + k8, mr0,mr1,mz0,mz1);

    // ---- A-dots (8), computed redundantly in-block ----
    {
      float p[8];
      p[0] = mr0[0]*mr0[0]+mr0[1]*mr0[1]+mr0[2]*mr0[2]+mr0[3]*mr0[3]
           + mr1[0]*mr1[0]+mr1[1]*mr1[1]+mr1[2]*mr1[2]+mr1[3]*mr1[3];
      p[1] = mr0[0]*xr0[0]+mr0[1]*xr0[1]+mr0[2]*xr0[2]+mr0[3]*xr0[3]
           + mr1[0]*xr1[0]+mr1[1]*xr1[1]+mr1[2]*xr1[2]+mr1[3]*xr1[3];
      p[3] = mz0[0]*mz0[0]+mz0[1]*mz0[1]+mz0[2]*mz0[2]+mz0[3]*mz0[3]
           + mz1[0]*mz1[0]+mz1[1]*mz1[1]+mz1[2]*mz1[2]+mz1[3]*mz1[3];
      p[4] = mz0[0]*xz0[0]+mz0[1]*xz0[1]+mz0[2]*xz0[2]+mz0[3]*xz0[3]
           + mz1[0]*xz1[0]+mz1[1]*xz1[1]+mz1[2]*xz1[2]+mz1[3]*xz1[3];
      p[2]=0.f; p[5]=0.f; p[6]=0.f; p[7]=0.f;
      #pragma unroll
      for(int i=0;i<4;i++){
        float brv=biasL0[k8+i], bzv=biasL1[k8+i], bhv=biasL2[k8+i];
        p[2]+=mr0[i]*brv; p[5]+=mz0[i]*bzv; p[6]+=hreg[i]*xh0[i]; p[7]+=hreg[i]*bhv;
      }
      #pragma unroll
      for(int i=0;i<4;i++){
        float brv=biasL0[k8+4+i], bzv=biasL1[k8+4+i], bhv=biasL2[k8+4+i];
        p[2]+=mr1[i]*brv; p[5]+=mz1[i]*bzv; p[6]+=hreg[4+i]*xh1[i]; p[7]+=hreg[4+i]*bhv;
      }
      #pragma unroll
      for(int d=0;d<8;d++){ p[d]+=__shfl_xor(p[d],16); p[d]+=__shfl_xor(p[d],32); }
      if(lane<16){
        #pragma unroll
        for(int d=0;d<8;d++) part[wv][lane][d]=p[d];
      }
    }
    __syncthreads();
    if(tid<128){
      int row=tid>>3, d=tid&7;
      float s=0;
      #pragma unroll
      for(int w2=0;w2<16;w2++) s += part[w2][row][d];
      dotsA[row][d]=s;
    }
    __syncthreads();

    // ---- gate coefficients (16 threads) ----
    if(tid<16){
      int b2 = tid;
      float s0=dotsA[b2][0], s1=dotsA[b2][1], s2=dotsA[b2][2];
      float s3=dotsA[b2][3], s4=dotsA[b2][4], s5=dotsA[b2][5];
      const float* px = pubX + (size_t)(ts*Bb+b2)*6;
      float xrxr=px[0], xrbr=px[1], xzxz=px[2], xzbz=px[3];
      float bbr=bbT[0], bbz=bbT[1];
      float nm=sqrtf(s0+EPSF), se=tanhf(nm)/nm;
      float uv=se*s1, uu=se*se*s0, vvr=xrxr;
      float den=1.f+2.f*uv+uu*vvr;
      float a1=(1.f+2.f*uv+vvr)*se/den, a2=(1.f-uu)/den;
      float uv2=a1*s2+a2*xrbr;
      float uu2=a1*a1*s0+2.f*a1*a2*s1+a2*a2*xrxr;
      float den2=1.f+2.f*uv2+uu2*bbr;
      float b1=(1.f+2.f*uv2+bbr)/den2, b2c=(1.f-uu2)/den2;
      float c1=b1*a1, c2=b1*a2, c3=b2c;
      float n2sq=c1*c1*s0+c2*c2*xrxr+c3*c3*bbr+2.f*(c1*c2*s1+c1*c3*s2+c2*c3*xrbr);
      float nn2=sqrtf(n2sq+EPSF);
      float s_r=atanhf(fminf(nn2,MAXNRM))/nn2;
      coefA[b2][0]=s_r*c1; coefA[b2][1]=s_r*c2; coefA[b2][2]=s_r*c3;
      float nmz=sqrtf(s3+EPSF), sez=tanhf(nmz)/nmz;
      float uvz=sez*s4, uuz=sez*sez*s3, vvz=xzxz;
      float denz=1.f+2.f*uvz+uuz*vvz;
      float az1=(1.f+2.f*uvz+vvz)*sez/denz, az2=(1.f-uuz)/denz;
      float uvz2=az1*s5+az2*xzbz;
      float uuz2=az1*az1*s3+2.f*az1*az2*s4+az2*az2*xzxz;
      float denz2=1.f+2.f*uvz2+uuz2*bbz;
      float bz1=(1.f+2.f*uvz2+bbz)/denz2, bz2=(1.f-uuz2)/denz2;
      float cz1=bz1*az1, cz2=bz1*az2, cz3=bz2;
      float nz2sq=cz1*cz1*s3+cz2*cz2*xzxz+cz3*cz3*bbz+2.f*(cz1*cz2*s4+cz1*cz3*s5+cz2*cz3*xzbz);
      float nnz2=sqrtf(nz2sq+EPSF);
      float s_z=atanhf(fminf(nnz2,MAXNRM))/nnz2;
      coefA[b2][3]=s_z*cz1; coefA[b2][4]=s_z*cz2; coefA[b2][5]=s_z*cz3;
    }
    __syncthreads();

    // ---- build ap A-fragment from regs (all threads, own slot) ----
    {
      float ca=coefA[nl][0], cb=coefA[nl][1], cc=coefA[nl][2];
      short8v lhv = *(const short8v*)&afAF[((size_t)wv*64+lane)*8];
      short8v o;
      #pragma unroll
      for(int i=0;i<4;i++){
        float r1 = sigm(ca*mr0[i] + cb*xr0[i] + cc*biasL0[k8+i]);
        o[i] = (short)f2bf(r1*bf2f(lhv[i]));
      }
      #pragma unroll
      for(int i=0;i<4;i++){
        float r1 = sigm(ca*mr1[i] + cb*xr1[i] + cc*biasL0[k8+4+i]);
        o[4+i] = (short)f2bf(r1*bf2f(lhv[4+i]));
      }
      __syncthreads();   // all waves done reading afAF(lh) for P2 — safe (post-gsyncA)
      *(short8v*)&afAF[((size_t)wv*64+lane)*8] = o;
    }
    __syncthreads();

    // ---- P5: matvec h via MFMA (waves 0..1), publish own slice ----
    if(wv < 2){
      int nt = wv;
      f32x4 acc = {0.f,0.f,0.f,0.f};
      #pragma unroll
      for(int kt2=0;kt2<16;kt2++){
        short8v av = *(const short8v*)&afAF[((size_t)kt2*64+lane)*8];
        short8v bv = *(const short8v*)&Wlds[((((size_t)2*16+kt2)*2+nt)*64+lane)*8];
        acc = __builtin_amdgcn_mfma_f32_16x16x32_bf16(av, bv, acc, 0,0,0);
      }
      int colg = g*32 + nt*16 + nl;
      #pragma unroll
      for(int rr=0;rr<4;rr++)
        stg_sc(Emh + (q*4+rr)*Hh + colg, acc[rr]);
    }
    gsync(2*ts+1);  // ---- sync B ----

    // ---- round B load: full mh into regs ----
    f32x4 mh0,mh1;
    ldg_sc8(Emh + nl*Hh + k8, mh0, mh1);

    // ---- B-dots (18), computed redundantly in-block ----
    {
      float cz1=coefA[nl][3], cz2=coefA[nl][4], cz3=coefA[nl][5];
      float p[18];
      #pragma unroll
      for(int d=0;d<18;d++) p[d]=0.f;
      #pragma unroll
      for(int i=0;i<8;i++){
        float mh = i<4 ? mh0[i] : mh1[i-4];
        float mz = i<4 ? mz0[i] : mz1[i-4];
        float xh = i<4 ? xh0[i] : xh1[i-4];
        float xz = i<4 ? xz0[i] : xz1[i-4];
        float bhv = biasL2[k8+i], bzv = biasL1[k8+i];
        float hv = hreg[i];
        float z = sigm(cz1*mz + cz2*xz + cz3*bzv);
        float eh=z*hv, em=z*mh, ex=z*xh, eb=z*bhv;
        p[0]+=mh*mh; p[1]+=mh*xh; p[2]+=mh*bhv; p[3]+=hv*mh;
        p[4]+=eh*eh; p[5]+=eh*em; p[6]+=eh*ex; p[7]+=eh*eb;
        p[8]+=em*em; p[9]+=em*ex; p[10]+=em*eb;
        p[11]+=ex*ex; p[12]+=ex*eb; p[13]+=eb*eb;
        p[14]+=hv*eh; p[15]+=hv*em; p[16]+=hv*ex; p[17]+=hv*eb;
      }
      #pragma unroll
      for(int d=0;d<18;d++){ p[d]+=__shfl_xor(p[d],16); p[d]+=__shfl_xor(p[d],32); }
      if(lane<16){
        #pragma unroll
        for(int d=0;d<18;d++) part[wv][lane][d]=p[d];
      }
    }
    __syncthreads();
    if(tid<288){
      int row=tid/18, d=tid%18;
      float s=0;
      #pragma unroll
      for(int w2=0;w2<16;w2++) s += part[w2][row][d];
      dotsB[row][d]=s;
    }
    __syncthreads();

    // ---- update coefficients (16 threads) ----
    if(tid<16){
      int b2 = tid;
      float d0=dotsB[b2][0], d1=dotsB[b2][1], d2=dotsB[b2][2], d3=dotsB[b2][3];
      float Ghh=dotsB[b2][4], Ghm=dotsB[b2][5], Ghx=dotsB[b2][6], Ghb=dotsB[b2][7];
      float Gmm=dotsB[b2][8], Gmx=dotsB[b2][9], Gmb=dotsB[b2][10];
      float Gxx=dotsB[b2][11], Gxb=dotsB[b2][12], Gbb=dotsB[b2][13];
      float Heh=dotsB[b2][14], Hem=dotsB[b2][15], Hex=dotsB[b2][16], Heb=dotsB[b2][17];
      const float* px = pubX + (size_t)(ts*Bb+b2)*6;
      float xhxh=px[4], xhbh=px[5];
      float hxh=dotsA[b2][6], hbh=dotsA[b2][7];
      float bbh=bbT[2]; float Shb=ShT[b2];
      float nm3=sqrtf(d0+EPSF), se3=tanhf(nm3)/nm3;
      float uvh=se3*d1, uuh=se3*se3*d0, vvh=xhxh;
      float denh=1.f+2.f*uvh+uuh*vvh;
      float a1p=(1.f+2.f*uvh+vvh)*se3/denh, a2p=(1.f-uuh)/denh;
      float uv2h=a1p*d2+a2p*xhbh;
      float uu2h=a1p*a1p*d0+2.f*a1p*a2p*d1+a2p*a2p*xhxh;
      float den2h=1.f+2.f*uv2h+uu2h*bbh;
      float b1p=(1.f+2.f*uv2h+bbh)/den2h, b2p=(1.f-uu2h)/den2h;
      float c1p=b1p*a1p, c2p=b1p*a2p, c3p=b2p;
      float h_htil=c1p*d3+c2p*hxh+c3p*hbh;
      float htil2=c1p*c1p*d0+c2p*c2p*xhxh+c3p*c3p*bbh
                +2.f*(c1p*c2p*d1+c1p*c3p*d2+c2p*c3p*xhbh);
      float denD=1.f-2.f*h_htil+Shb*htil2;
      float dd1=(1.f-2.f*h_htil+htil2)/denD, dd2=(1.f-Shb)/denD;
      float g0=-dd1, g1=dd2*c1p, g2=dd2*c2p, g3=dd2*c3p;
      float del2=g0*g0*Shb+g1*g1*d0+g2*g2*xhxh+g3*g3*bbh
               +2.f*(g0*g1*d3+g0*g2*hxh+g0*g3*hbh+g1*g2*d1+g1*g3*d2+g2*g3*xhbh);
      float ndl=sqrtf(del2+EPSF);
      float sld=atanhf(fminf(ndl,MAXNRM))/ndl;
      float Qe=g0*g0*Ghh+g1*g1*Gmm+g2*g2*Gxx+g3*g3*Gbb
             +2.f*(g0*g1*Ghm+g0*g2*Ghx+g0*g3*Ghb+g1*g2*Gmx+g1*g3*Gmb+g2*g3*Gxb);
      float Le=g0*Heh+g1*Hem+g2*Hex+g3*Heb;
      float Sww=sld*sld*Qe;
      float Shw=sld*Le;
      float nw=sqrtf(Sww+EPSF), sew=tanhf(nw)/nw;
      float uvw=sew*Shw, uuw=Shb, vvw=sew*sew*Sww;
      float denw=1.f+2.f*uvw+uuw*vvw;
      float p1=(1.f+2.f*uvw+vvw)/denw, p2=(1.f-uuw)/denw;
      float q1=p1, q2=p2*sew;
      float n2h=q1*q1*Shb+2.f*q1*q2*Shw+q2*q2*Sww;
      float nrm=sqrtf(n2h+EPSF);
      float scl=fminf(1.f, MAXNRM/nrm);
      float Shn=scl*scl*n2h;
      float nh2=sqrtf(Shn+EPSF);
      float slh=atanhf(fminf(nh2,MAXNRM))/nh2;
      coefB[b2][0]=scl*q1; coefB[b2][1]=scl*q2*sld;
      coefB[b2][2]=g0; coefB[b2][3]=g1; coefB[b2][4]=g2; coefB[b2][5]=g3;
      coefB[b2][6]=slh;
      ShT[b2]=Shn;
    }
    __syncthreads();

    // ---- replicated h update (all in regs); write lh frag + own Xout slice ----
    {
      float cz1=coefA[nl][3], cz2=coefA[nl][4], cz3=coefA[nl][5];
      float qc1=coefB[nl][0], qc2=coefB[nl][1];
      float g0=coefB[nl][2], g1=coefB[nl][3], g2=coefB[nl][4], g3=coefB[nl][5];
      float slh=coefB[nl][6];
      short8v o;
      #pragma unroll
      for(int i=0;i<4;i++){
        float z = sigm(cz1*mz0[i] + cz2*xz0[i] + cz3*biasL1[k8+i]);
        float dl = g0*hreg[i] + g1*mh0[i] + g2*xh0[i] + g3*biasL2[k8+i];
        float hn = qc1*hreg[i] + qc2*z*dl;
        hreg[i]=hn; o[i]=(short)f2bf(slh*hn);
      }
      #pragma unroll
      for(int i=0;i<4;i++){
        float z = sigm(cz1*mz1[i] + cz2*xz1[i] + cz3*biasL1[k8+4+i]);
        float dl = g0*hreg[4+i] + g1*mh1[i] + g2*xh1[i] + g3*biasL2[k8+4+i];
        float hn = qc1*hreg[4+i] + qc2*z*dl;
        hreg[4+i]=hn; o[4+i]=(short)f2bf(slh*hn);
      }
      *(short8v*)&afAF[((size_t)wv*64+lane)*8] = o;
      if(wv == g){
        f32x4 h0, h1;
        #pragma unroll
        for(int i=0;i<4;i++){ h0[i]=hreg[i]; h1[i]=hreg[4+i]; }
        *(f32x4*)(Xout + rxb) = h0;
        *(f32x4*)(Xout + rxb + 4) = h1;
      }
    }
    __syncthreads();
  }
}

// ---------------- fused MLR + online softmax partials ----------------
__global__ __launch_bounds__(256) void k_mlr(const float* __restrict__ X,
    const float* __restrict__ P, const float* __restrict__ A,
    const float* __restrict__ pp, const float* __restrict__ aa, const float* __restrict__ pa,
    const int* __restrict__ tgt, float* __restrict__ pm, float* __restrict__ tl){
  constexpr int RT = 32;
  int split = blockIdx.x;      // 0..7
  int rg = blockIdx.y;         // 0..63
  int rbase = rg*RT;
  __shared__ float Xs[RT][516];
  __shared__ float par[8][RT];
  __shared__ float ms[8][RT][2];
  __shared__ float xxs[RT];
  int tid = threadIdx.x;
  #pragma unroll
  for(int u=0;u<16;u++){
    int fi = u*256 + tid;
    int row = fi >> 7, c4 = fi & 127;
    float4 v = ld4(X + (size_t)(rbase+row)*Hh + c4*4);
    st4(&Xs[row][c4*4], v);
  }
  __syncthreads();
  { int r = tid & 31, seg = tid >> 5;
    float s = 0;
    for(int k=seg*64;k<seg*64+64;k++){ float x = Xs[r][k]; s += x*x; }
    par[seg][r] = s; }
  __syncthreads();
  if(tid < RT){ float s=0; for(int i=0;i<8;i++) s += par[i][tid]; xxs[tid]=s; }
  __syncthreads();
  int r = tid & 31, vi = tid >> 5;
  int rr = rbase + r;
  int tt = rr >> 4, bbr2 = rr & 15;
  int tok = tgt[bbr2*Ss + tt];
  float xx = xxs[r];
  float m = -3.0e38f, sacc = 0.f;
  int v0 = split*1250, v1e = v0 + 1250;
  const float4* Xrow = (const float4*)&Xs[r][0];
  for(int vbv=v0; vbv<v1e; vbv+=8){
    int v = vbv + vi;
    if(v < v1e){
      float px=0, xa=0;
      const float4* Pr = (const float4*)(P + (size_t)v*Hh);
      const float4* Ar = (const float4*)(A + (size_t)v*Hh);
      #pragma unroll 4
      for(int k4=0;k4<128;k4++){
        float4 xv = Xrow[k4];
        float4 pvv = Pr[k4]; float4 av = Ar[k4];
        px += dot4(xv,pvv); xa += dot4(xv,av);
      }
      float ppv = pp[v], aav = aa[v], pav = pa[v];
      float al = 1.f - 2.f*px + xx;
      float be = 1.f - ppv;
      float gm = 1.f - 2.f*px + ppv*xx;
      float da = (-al*pav + be*xa)/gm;
      float dd = (al*al*ppv - 2.f*al*be*px + be*be*xx)/(gm*gm);
      float lam = 2.f/(1.f - ppv);
      float arg = 2.f*da/((1.f - dd)*aav + EPSF);
      float lg = lam*aav*asinhf(arg);
      if(v == tok) tl[rr] = lg;
      if(lg > m){ sacc = sacc*expf(m - lg) + 1.f; m = lg; }
      else sacc += expf(lg - m);
    }
  }
  ms[vi][r][0] = m; ms[vi][r][1] = sacc;
  __syncthreads();
  if(vi==0){
    float M = -3.0e38f;
    for(int i=0;i<8;i++) M = fmaxf(M, ms[i][r][0]);
    float Ssum = 0.f;
    for(int i=0;i<8;i++) Ssum += ms[i][r][1]*expf(ms[i][r][0]-M);
    pm[((size_t)rr*8 + split)*2 + 0] = M;
    pm[((size_t)rr*8 + split)*2 + 1] = Ssum;
  }
}

// ---------------- final merge + mean NLL ----------------
__global__ void k_final(const float* __restrict__ pm, const float* __restrict__ tl, float* __restrict__ out){
  int tid = threadIdx.x;
  __shared__ float sred[4];
  float acc = 0.f;
  for(int q=0;q<8;q++){
    int rr = q*256 + tid;
    float M = -3.0e38f;
    for(int s=0;s<8;s++) M = fmaxf(M, pm[((size_t)rr*8+s)*2]);
    float Ssum = 0.f;
    for(int s=0;s<8;s++) Ssum += pm[((size_t)rr*8+s)*2+1]*expf(pm[((size_t)rr*8+s)*2]-M);
    acc += (M + logf(Ssum)) - tl[rr];
  }
  for(int o=32;o;o>>=1) acc += __shfl_down(acc,o);
  if((tid&63)==0) sred[tid>>6] = acc;
  __syncthreads();
  if(tid==0) out[0] = (sred[0]+sred[1]+sred[2]+sred[3]) / 2048.f;
}

extern "C" void kernel_launch(void* const* d_in, const int* in_sizes, int n_in,
                              void* d_out, int out_size, void* d_ws, size_t ws_size,
                              hipStream_t stream){
  const int* inp = (const int*)d_in[0];
  const int* tgt = (const int*)d_in[1];
  const float* E  = (const float*)d_in[2];
  const float* Wr = (const float*)d_in[3];
  const float* Wz = (const float*)d_in[4];
  const float* Wh = (const float*)d_in[5];
  const float* Ur = (const float*)d_in[6];
  const float* Uz = (const float*)d_in[7];
  const float* Uh = (const float*)d_in[8];
  const float* br = (const float*)d_in[9];
  const float* bz = (const float*)d_in[10];
  const float* bh = (const float*)d_in[11];
  const float* P  = (const float*)d_in[12];
  const float* A  = (const float*)d_in[13];
  float* out = (float*)d_out;
  float* w = (float*)d_ws;
  size_t o = 0;
  auto take = [&](size_t n){ float* p = w + o; o += n; return p; };
  float* Xa  = take((size_t)Nn*Hh);
  float* Xb  = take((size_t)Nn*Hh);
  float* LX  = take((size_t)Nn*Hh);
  float* XR  = take((size_t)Nn*Hh);
  float* XZ  = take((size_t)Nn*Hh);
  float* XH  = take((size_t)Nn*Hh);
  ushort* Wp = (ushort*)take(1179648);
  float* pubX = take((size_t)Nn*6);
  float* Emr = take(8192);
  float* Emz = take(8192);
  float* Emh = take(8192);
  float* pp  = take(10240);
  float* aa  = take(10240);
  float* pa  = take(10240);
  float* pm  = take((size_t)Nn*8*2);
  float* tl  = take((size_t)Nn);
  int* cnt   = (int*)take(Ll*Ss*2);
  if(ws_size < o*sizeof(float)) return;

  hipMemsetAsync(cnt, 0, Ll*Ss*2*sizeof(int), stream);
  hipLaunchKernelGGL(k_pack, dim3(NBLK,9), dim3(1024), 0, stream, Wr,Wz,Wh, Wp);
  hipLaunchKernelGGL(k_pav, dim3(2500), dim3(256), 0, stream, P,A, pp,aa,pa);
  hipLaunchKernelGGL(k_embed, dim3(Nn), dim3(128), 0, stream, inp, E, Xa);
  float* cur = Xa; float* nxt = Xb;
  for(int l=0;l<Ll;l++){
    hipLaunchKernelGGL(k_logmap, dim3(Nn), dim3(128), 0, stream, cur, LX);
    hipLaunchKernelGGL(k_gemm, dim3(24,32), dim3(256), 0, stream, LX,
                       Ur + (size_t)l*Hh*Hh, Uz + (size_t)l*Hh*Hh, Uh + (size_t)l*Hh*Hh,
                       XR, XZ, XH);
    hipLaunchKernelGGL(k_expmap, dim3(Nn,3), dim3(128), 0, stream, XR,XZ,XH);
    hipLaunchKernelGGL(k_predots, dim3(Nn), dim3(128), 0, stream, XR,XZ,XH,
                       br + l*Hh, bz + l*Hh, bh + l*Hh, pubX);
    hipLaunchKernelGGL(k_scan5, dim3(NBLK), dim3(1024), 0, stream, XR,XZ,XH,
                       Wp + (size_t)l*NBLK*49152,
                       br + l*Hh, bz + l*Hh, bh + l*Hh,
                       pubX, Emr, Emz, Emh, cnt + l*Ss*2, nxt);
    float* tmp = cur; cur = nxt; nxt = tmp;
  }
  hipLaunchKernelGGL(k_mlr, dim3(8,64), dim3(256), 0, stream, cur, P, A, pp,aa,pa, tgt, pm, tl);
  hipLaunchKernelGGL(k_final, dim3(1), dim3(256), 0, stream, pm, tl, out);
}